// Round 13
// baseline (313.627 us; speedup 1.0000x reference)
//
#include <hip/hip_runtime.h>
#include <hip/hip_cooperative_groups.h>
#include <cstdint>

namespace cg = cooperative_groups;

#define RNG_PARTITIONABLE 1

// ---------------- Threefry-2x32 (exact JAX schedule) ----------------
__host__ __device__ inline void tf2x32(uint32_t k0, uint32_t k1,
                                       uint32_t x0, uint32_t x1,
                                       uint32_t& o0, uint32_t& o1) {
  const uint32_t k2 = k0 ^ k1 ^ 0x1BD11BDAu;
#define ROT(v, r) (((v) << (r)) | ((v) >> (32 - (r))))
#define R4(a,b,c,d) \
  x0 += x1; x1 = ROT(x1, a); x1 ^= x0; \
  x0 += x1; x1 = ROT(x1, b); x1 ^= x0; \
  x0 += x1; x1 = ROT(x1, c); x1 ^= x0; \
  x0 += x1; x1 = ROT(x1, d); x1 ^= x0;
  x0 += k0; x1 += k1;
  R4(13,15,26,6)   x0 += k1; x1 += k2 + 1u;
  R4(17,29,16,24)  x0 += k2; x1 += k0 + 2u;
  R4(13,15,26,6)   x0 += k0; x1 += k1 + 3u;
  R4(17,29,16,24)  x0 += k1; x1 += k2 + 4u;
  R4(13,15,26,6)   x0 += k2; x1 += k0 + 5u;
  o0 = x0; o1 = x1;
#undef R4
#undef ROT
}

// ---------------- exact (contraction-free, IEEE) IoU ----------------
__device__ __forceinline__ float iou_fn(float ax0, float ay0, float ax1, float ay1,
                                        float g0, float g1, float g2, float g3,
                                        float area_a, float area_g) {
  float ix0 = fmaxf(ax0, g0);
  float iy0 = fmaxf(ay0, g1);
  float ix1 = fminf(ax1, g2);
  float iy1 = fminf(ay1, g3);
  float iw = fmaxf(__fsub_rn(ix1, ix0), 0.0f);
  float ih = fmaxf(__fsub_rn(iy1, iy0), 0.0f);
  float inter = __fmul_rn(iw, ih);
  float denom = __fadd_rn(__fsub_rn(__fadd_rn(area_a, area_g), inter), 1e-5f);
  return __fdiv_rn(inter, denom);
}

__device__ __forceinline__ float area_fn(float x0, float y0, float x1, float y1) {
  return __fmul_rn(fmaxf(__fsub_rn(x1, x0), 0.0f), fmaxf(__fsub_rn(y1, y0), 0.0f));
}

// ---------------- mega helpers (full-wave uniform calls) ----------------
__device__ __forceinline__ void scan_anchor(int i, int N,
    const float4* __restrict__ anch, const float4* sg, int* smax, int G,
    float Wimg, float Himg, int l,
    float4& a, bool& inside, float& area_a, float& best, int& bj) {
  a = make_float4(0.f, 0.f, 0.f, 0.f);
  inside = false; area_a = 0.f;
  float ex0 = INFINITY, ey0 = INFINITY, ex1 = -INFINITY, ey1 = -INFINITY;
  if (i < N) {
    a = anch[i];
    inside = (a.x >= 0.f) && (a.y >= 0.f) && (a.z < Wimg) && (a.w < Himg);
    if (inside) { ex0 = a.x; ey0 = a.y; ex1 = a.z; ey1 = a.w; }
    area_a = area_fn(a.x, a.y, a.z, a.w);
  }
  float wx0 = ex0, wy0 = ey0, wx1 = ex1, wy1 = ey1;
  #pragma unroll
  for (int d = 32; d; d >>= 1) {
    wx0 = fminf(wx0, __shfl_xor(wx0, d));
    wy0 = fminf(wy0, __shfl_xor(wy0, d));
    wx1 = fmaxf(wx1, __shfl_xor(wx1, d));
    wy1 = fmaxf(wy1, __shfl_xor(wy1, d));
  }
  bool p0 = false, p1 = false;
  if (l < G) { float4 p = sg[l];      p0 = (wx0 < p.z) && (p.x < wx1) && (wy0 < p.w) && (p.y < wy1); }
  if (l + 64 < G) { float4 p = sg[l + 64]; p1 = (wx0 < p.z) && (p.x < wx1) && (wy0 < p.w) && (p.y < wy1); }
  unsigned long long m0 = __ballot(p0);
  unsigned long long m1 = __ballot(p1);
  best = inside ? 0.0f : -1.0f;        // all-skip rows: argmax 0 (matches ref)
  bj = 0;
  const int lane0 = (l == 0);
  while (m0) {                                          // j ascending [0,64)
    int j = __ffsll(m0) - 1; m0 &= m0 - 1;
    float4 p = sg[j];
    float ag = area_fn(p.x, p.y, p.z, p.w);
    float iou = iou_fn(a.x, a.y, a.z, a.w, p.x, p.y, p.z, p.w, area_a, ag);
    float mval = inside ? iou : -1.0f;
    if (mval > best) { best = mval; bj = j; }           // strict >: FIRST argmax
    float w = mval;
    #pragma unroll
    for (int d = 32; d; d >>= 1) w = fmaxf(w, __shfl_xor(w, d));
    if (lane0) atomicMax(&smax[j], __float_as_int(w));
  }
  while (m1) {                                          // then [64,128)
    int j = __ffsll(m1) - 1 + 64; m1 &= m1 - 1;
    float4 p = sg[j];
    float ag = area_fn(p.x, p.y, p.z, p.w);
    float iou = iou_fn(a.x, a.y, a.z, a.w, p.x, p.y, p.z, p.w, area_a, ag);
    float mval = inside ? iou : -1.0f;
    if (mval > best) { best = mval; bj = j; }
    float w = mval;
    #pragma unroll
    for (int d = 32; d; d >>= 1) w = fmaxf(w, __shfl_xor(w, d));
    if (lane0) atomicMax(&smax[j], __float_as_int(w));
  }
}

__device__ __forceinline__ bool gbest_anchor(int i, int N, bool inside, int cls,
    float4 a, float area_a, const float4* sg, const float* sgm,
    const int* zlist, int zn, int G, int l) {
  const bool need = (i < N) && inside && (cls == 1);
  bool gbest = false;
  if (__any(need)) {
    float nx0 = need ? a.x : INFINITY,  ny0 = need ? a.y : INFINITY;
    float nx1 = need ? a.z : -INFINITY, ny1 = need ? a.w : -INFINITY;
    #pragma unroll
    for (int d = 32; d; d >>= 1) {
      nx0 = fminf(nx0, __shfl_xor(nx0, d));
      ny0 = fminf(ny0, __shfl_xor(ny0, d));
      nx1 = fmaxf(nx1, __shfl_xor(nx1, d));
      ny1 = fmaxf(ny1, __shfl_xor(ny1, d));
    }
    bool q0 = false, q1 = false;
    if (l < G) { float4 p = sg[l];      q0 = (nx0 < p.z) && (p.x < nx1) && (ny0 < p.w) && (p.y < ny1); }
    if (l + 64 < G) { float4 p = sg[l + 64]; q1 = (nx0 < p.z) && (p.x < nx1) && (ny0 < p.w) && (p.y < ny1); }
    unsigned long long n0 = __ballot(q0);
    unsigned long long n1 = __ballot(q1);
    while (n0) {
      int j = __ffsll(n0) - 1; n0 &= n0 - 1;
      float4 p = sg[j];
      float ag = area_fn(p.x, p.y, p.z, p.w);
      float iou = iou_fn(a.x, a.y, a.z, a.w, p.x, p.y, p.z, p.w, area_a, ag);
      gbest = gbest | (need && (iou == sgm[j]));
    }
    while (n1) {
      int j = __ffsll(n1) - 1 + 64; n1 &= n1 - 1;
      float4 p = sg[j];
      float ag = area_fn(p.x, p.y, p.z, p.w);
      float iou = iou_fn(a.x, a.y, a.z, a.w, p.x, p.y, p.z, p.w, area_a, ag);
      gbest = gbest | (need && (iou == sgm[j]));
    }
    const int zc = min(zn, 16);
    for (int z = 0; z < zc; ++z) {     // degenerate gmax==0: no-overlap <=> iou==0==gmax
      float4 p = sg[zlist[z]];
      bool ov = (a.x < p.z) && (p.x < a.z) && (a.y < p.w) && (p.y < a.w);
      gbest = gbest | (need && !ov);
    }
  }
  return gbest;
}

__device__ __forceinline__ unsigned rng_m(int i, int lab,
    uint32_t kf0, uint32_t kf1, uint32_t kb0, uint32_t kb1, int N) {
  uint32_t K0 = (lab == 1) ? kf0 : kb0;
  uint32_t K1 = (lab == 1) ? kf1 : kb1;
  uint32_t o0, o1;
#if RNG_PARTITIONABLE
  tf2x32(K0, K1, 0u, (uint32_t)i, o0, o1);
  return (o0 ^ o1) >> 9;
#else
  int NH = N >> 1;
  if (i < NH) { tf2x32(K0, K1, (uint32_t)i, (uint32_t)(i + NH), o0, o1); return o0 >> 9; }
  tf2x32(K0, K1, (uint32_t)(i - NH), (uint32_t)i, o0, o1); return o1 >> 9;
#endif
}

__device__ __forceinline__ void write_out_one(int i, int N, int lab, unsigned mm,
    bool inside, float4 a, int bj, const float4* sg,
    const unsigned long long* sthr, int ne, float* out) {
  if (i >= N) return;
  int labf = lab;
  if (labf >= 0) {
    int s = labf ? 0 : 1;
    unsigned long long key = ((unsigned long long)mm << 19) | (unsigned)i;
    if (key >= sthr[s]) labf = -1;
  }
  out[i] = (float)labf;
  float4 tg = make_float4(0.0f, 0.0f, 0.0f, 0.0f);
  if (inside) {
    float4 g = sg[bj];
    float ew = __fadd_rn(__fsub_rn(a.z, a.x), 1.0f);
    float eh = __fadd_rn(__fsub_rn(a.w, a.y), 1.0f);
    float ecx = __fadd_rn(a.x, __fmul_rn(0.5f, ew));
    float ecy = __fadd_rn(a.y, __fmul_rn(0.5f, eh));
    float gw = __fadd_rn(__fsub_rn(g.z, g.x), 1.0f);
    float gh = __fadd_rn(__fsub_rn(g.w, g.y), 1.0f);
    float gcx = __fadd_rn(g.x, __fmul_rn(0.5f, gw));
    float gcy = __fadd_rn(g.y, __fmul_rn(0.5f, gh));
    tg = make_float4(__fdiv_rn(__fsub_rn(gcx, ecx), ew),
                     __fdiv_rn(__fsub_rn(gcy, ecy), eh),
                     logf(__fdiv_rn(gw, ew)),
                     logf(__fdiv_rn(gh, eh)));
  }
  reinterpret_cast<float4*>(out + (size_t)N)[i] = tg;
  float bw = (labf == 1) ? 1.0f : 0.0f;
  reinterpret_cast<float4*>(out + 5 * (size_t)N)[i] = make_float4(bw, bw, bw, bw);
  float ov = (labf >= 0) ? __fdiv_rn(1.0f, (float)ne) : 0.0f;
  reinterpret_cast<float4*>(out + 9 * (size_t)N)[i] = make_float4(ov, ov, ov, ov);
}

// ---------------- mega: 2 anchors/thread, 4 grid syncs -----------------------
// gmax explicitly zeroed (S0 before accumulation) -- no poison assumptions,
// idempotent across graph replays. hist/counters/colcnt re-zeroed every call.
__global__ void __launch_bounds__(256, 3) mega(
    const float4* __restrict__ anch, const float* __restrict__ gt,
    const float* __restrict__ info, float* __restrict__ out,
    int* __restrict__ gmax, int* __restrict__ hist,
    int* __restrict__ counters, int* __restrict__ colcnt,
    unsigned long long* __restrict__ collected,
    uint32_t kf0, uint32_t kf1, uint32_t kb0, uint32_t kb1,
    int N, int G, int hs) {
  cg::grid_group grid = cg::this_grid();
  __shared__ float4 sg[128];
  __shared__ int smax[128];
  __shared__ float sgm[128];
  __shared__ int zlist[16];
  __shared__ int zn;
  __shared__ int cnt_s[2];
  __shared__ int part[256];
  __shared__ int sbin[2], srank[2];
  __shared__ unsigned long long skeys[1024];
  __shared__ unsigned long long sthr[2];

  const int t = threadIdx.x;
  const int gtid = blockIdx.x * 256 + t;
  const int i0 = gtid;
  const int i1 = gtid + hs;
  const int l = t & 63;

  // ---- P0: zero scratch + load gts ----
  if (gtid < 2 * 16384) hist[gtid] = 0;
  if (gtid < 2) { counters[gtid] = 0; colcnt[gtid] = 0; }
  if (gtid < G) gmax[gtid] = 0;
  for (int q = t; q < G; q += 256) {
    float g0 = gt[5*q], g1 = gt[5*q+1], g2 = gt[5*q+2], g3 = gt[5*q+3];
    sg[q] = make_float4(g0, g1, g2, g3);
    smax[q] = 0;
  }
  grid.sync();                                          // ---- S0 ----

  // ---- P1: anchor scans (both halves) -> smax -> gmax ----
  const float Himg = info[0], Wimg = info[1];
  float4 a0, a1; bool in0, in1; float ar0, ar1, b0, b1; int bj0, bj1;
  scan_anchor(i0, N, anch, sg, smax, G, Wimg, Himg, l, a0, in0, ar0, b0, bj0);
  scan_anchor(i1, N, anch, sg, smax, G, Wimg, Himg, l, a1, in1, ar1, b1, bj1);
  __syncthreads();
  for (int q = t; q < G; q += 256) {
    int v = smax[q];
    if (v != 0) atomicMax(&gmax[q], v);
  }
  grid.sync();                                          // ---- S1 ----

  // ---- P2: labels + rng + hist ----
  if (t == 0) zn = 0;
  if (t < 2) cnt_s[t] = 0;
  __syncthreads();
  for (int q = t; q < G; q += 256) {
    float gm = __int_as_float(gmax[q]);
    sgm[q] = gm;
    if (gm == 0.0f) { int p = atomicAdd(&zn, 1); if (p < 16) zlist[p] = q; }
  }
  __syncthreads();
  const int cls0 = (b0 < 0.3f) ? 0 : ((b0 >= 0.7f) ? 2 : 1);
  const int cls1 = (b1 < 0.3f) ? 0 : ((b1 >= 0.7f) ? 2 : 1);
  bool gb0 = gbest_anchor(i0, N, in0, cls0, a0, ar0, sg, sgm, zlist, zn, G, l);
  bool gb1 = gbest_anchor(i1, N, in1, cls1, a1, ar1, sg, sgm, zlist, zn, G, l);
  int lab0 = -1, lab1 = -1;
  if (i0 < N && in0) lab0 = (cls0 == 0) ? 0 : ((cls0 == 2) ? 1 : (gb0 ? 1 : -1));
  if (i1 < N && in1) lab1 = (cls1 == 0) ? 0 : ((cls1 == 2) ? 1 : (gb1 ? 1 : -1));
  {
    unsigned long long f0 = __ballot(lab0 == 1), z0 = __ballot(lab0 == 0);
    unsigned long long f1 = __ballot(lab1 == 1), z1 = __ballot(lab1 == 0);
    if ((t & 63) == 0) {
      int cf = __popcll(f0) + __popcll(f1);
      int cb = __popcll(z0) + __popcll(z1);
      if (cf) atomicAdd(&cnt_s[0], cf);
      if (cb) atomicAdd(&cnt_s[1], cb);
    }
    __syncthreads();
    if (t == 0) {
      if (cnt_s[0]) atomicAdd(&counters[0], cnt_s[0]);
      if (cnt_s[1]) atomicAdd(&counters[1], cnt_s[1]);
    }
  }
  unsigned mm0 = rng_m(i0, lab0, kf0, kf1, kb0, kb1, N);
  unsigned mm1 = rng_m(i1, lab1, kf0, kf1, kb0, kb1, N);
  if (i0 < N && lab0 >= 0) {
    int s = lab0 ? 0 : 1;
    unsigned long long key = ((unsigned long long)mm0 << 19) | (unsigned)i0;
    atomicAdd(&hist[s * 16384 + (int)(key >> 28)], 1);
  }
  if (i1 < N && lab1 >= 0) {
    int s = lab1 ? 0 : 1;
    unsigned long long key = ((unsigned long long)mm1 << 19) | (unsigned)i1;
    atomicAdd(&hist[s * 16384 + (int)(key >> 28)], 1);
  }
  grid.sync();                                          // ---- S2 ----

  // ---- P3: replicated resolveA + collect ----
  {
    int fgc = counters[0], bgc = counters[1];
    int fgk = min(fgc, 128);
    int Ks[2] = { fgk, min(256 - fgk, bgc) };
    for (int s = 0; s < 2; ++s) {
      int K = Ks[s];
      if (K <= 0) {
        if (t == 0) { sbin[s] = -1; srank[s] = 0; }
        __syncthreads();
        continue;
      }
      const int* h = hist + s * 16384;
      int sum = 0;
      #pragma unroll
      for (int b = 0; b < 64; ++b) sum += h[t * 64 + b];
      part[t] = sum;
      __syncthreads();
      if (t == 0) {
        int cum = 0, rch = K, chunk = 255;
        for (int q = 0; q < 256; ++q) {
          if (cum + part[q] >= K) { chunk = q; rch = K - cum; break; }
          cum += part[q];
        }
        int cum2 = 0;
        for (int b = 0; b < 64; ++b) {
          int hv = h[chunk * 64 + b];
          if (cum2 + hv >= rch) { sbin[s] = chunk * 64 + b; srank[s] = rch - cum2; break; }
          cum2 += hv;
        }
      }
      __syncthreads();
    }
  }
  if (i0 < N && lab0 >= 0) {
    int s = lab0 ? 0 : 1;
    unsigned long long key = ((unsigned long long)mm0 << 19) | (unsigned)i0;
    if ((int)(key >> 28) == sbin[s]) {
      int slot = atomicAdd(&colcnt[s], 1);
      if (slot < 1024) collected[s * 1024 + slot] = key;
    }
  }
  if (i1 < N && lab1 >= 0) {
    int s = lab1 ? 0 : 1;
    unsigned long long key = ((unsigned long long)mm1 << 19) | (unsigned)i1;
    if ((int)(key >> 28) == sbin[s]) {
      int slot = atomicAdd(&colcnt[s], 1);
      if (slot < 1024) collected[s * 1024 + slot] = key;
    }
  }
  grid.sync();                                          // ---- S3 ----

  // ---- P4: replicated resolveB + outputs ----
  {
    int fgc = counters[0], bgc = counters[1];
    int fgk = min(fgc, 128);
    int Ks[2] = { fgk, min(256 - fgk, bgc) };
    for (int s = 0; s < 2; ++s) {
      if (Ks[s] <= 0) {
        if (t == 0) sthr[s] = 0ull;
        __syncthreads(); __syncthreads();
        continue;
      }
      int n = min(colcnt[s], 1024);
      int r = srank[s];
      for (int kk = t; kk < n; kk += 256) skeys[kk] = collected[s * 1024 + kk];
      __syncthreads();
      for (int kk = t; kk < n; kk += 256) {
        unsigned long long k = skeys[kk];
        int rank = 0;
        for (int u = 0; u < n; ++u) rank += (skeys[u] < k);
        if (rank == r - 1) sthr[s] = k + 1ull;          // keep iff key < thr
      }
      __syncthreads();
    }
    const int ne = fgk + min(256 - fgk, bgc);
    write_out_one(i0, N, lab0, mm0, in0, a0, bj0, sg, sthr, ne, out);
    write_out_one(i1, N, lab1, mm1, in1, a1, bj1, sg, sthr, ne, out);
  }
}

// ================== fallback path: proven r11 5-kernel pipeline ==============
__global__ void __launch_bounds__(256) K1a(const float4* __restrict__ anch,
        const float* __restrict__ gt, const float* __restrict__ info,
        int* __restrict__ meta, float* __restrict__ slab,
        int* __restrict__ hist, int* __restrict__ zbase, int N, int G) {
  __shared__ float4 sg[128];
  __shared__ int smax[128];
  const int t = threadIdx.x;
  const int gtid = blockIdx.x * 256 + t;
  if (gtid < 2 * 16384) hist[gtid] = 0;
  if (gtid < 4) zbase[gtid] = 0;
  for (int q = t; q < G; q += 256) {
    float g0 = gt[5*q], g1 = gt[5*q+1], g2 = gt[5*q+2], g3 = gt[5*q+3];
    sg[q] = make_float4(g0, g1, g2, g3);
    smax[q] = 0;
  }
  __syncthreads();
  const float Himg = info[0], Wimg = info[1];
  const int l = t & 63;
  float4 a; bool inside; float area_a, best; int bj;
  scan_anchor(gtid, N, anch, sg, smax, G, Wimg, Himg, l, a, inside, area_a, best, bj);
  if (gtid < N) {
    int cls = (best < 0.3f) ? 0 : ((best >= 0.7f) ? 2 : 1);
    meta[gtid] = bj | (inside ? 512 : 0) | (cls << 10);
  }
  __syncthreads();
  for (int q = t; q < G; q += 256)
    slab[(size_t)blockIdx.x * 128 + q] = __int_as_float(smax[q]);
}

__global__ void __launch_bounds__(256) kgtB(const float* __restrict__ slab,
                                            int* __restrict__ gmax, int nchunks) {
  __shared__ float red[256];
  const int t = threadIdx.x;
  const int j = blockIdx.x;
  float best = 0.0f;
  for (int c = t; c < nchunks; c += 256)
    best = fmaxf(best, slab[(size_t)c * 128 + j]);
  red[t] = best;
  __syncthreads();
  #pragma unroll
  for (int s = 128; s > 0; s >>= 1) {
    if (t < s) red[t] = fmaxf(red[t], red[t + s]);
    __syncthreads();
  }
  if (t == 0) gmax[j] = __float_as_int(red[0]);
}

__global__ void __launch_bounds__(256) K1c(const float4* __restrict__ anch,
        const float* __restrict__ gt, const int* __restrict__ gmax,
        int* __restrict__ meta, unsigned* __restrict__ marr,
        int* __restrict__ counters, int* __restrict__ hist,
        uint32_t kf0, uint32_t kf1, uint32_t kb0, uint32_t kb1,
        int N, int G) {
  __shared__ float4 sg[128];
  __shared__ float sgm[128];
  __shared__ int cnt_s[2];
  __shared__ int zlist[16];
  __shared__ int zn;
  const int t = threadIdx.x;
  if (t == 0) zn = 0;
  if (t < 2) cnt_s[t] = 0;
  for (int q = t; q < G; q += 256) {
    float g0 = gt[5*q], g1 = gt[5*q+1], g2 = gt[5*q+2], g3 = gt[5*q+3];
    sg[q] = make_float4(g0, g1, g2, g3);
    float gm = __int_as_float(gmax[q]);
    sgm[q] = gm;
    if (gm == 0.0f) { int p = atomicAdd(&zn, 1); if (p < 16) zlist[p] = q; }
  }
  __syncthreads();
  const int i = blockIdx.x * 256 + t;
  const int l = t & 63;
  int mt = 0; bool inside = false; int cls = 0;
  float4 a = make_float4(0.f, 0.f, 0.f, 0.f);
  float area_a = 0.f;
  if (i < N) {
    mt = meta[i];
    inside = (mt >> 9) & 1;
    cls = (mt >> 10) & 3;
    a = anch[i];
    area_a = area_fn(a.x, a.y, a.z, a.w);
  }
  bool gbest = gbest_anchor(i, N, inside, cls, a, area_a, sg, sgm, zlist, zn, G, l);
  int lab = -1;
  if (i < N && inside)
    lab = (cls == 0) ? 0 : ((cls == 2) ? 1 : (gbest ? 1 : -1));
  unsigned long long bf = __ballot(lab == 1), bb = __ballot(lab == 0);
  if ((t & 63) == 0) {
    if (bf) atomicAdd(&cnt_s[0], __popcll(bf));
    if (bb) atomicAdd(&cnt_s[1], __popcll(bb));
  }
  __syncthreads();
  if (t == 0) {
    if (cnt_s[0]) atomicAdd(&counters[0], cnt_s[0]);
    if (cnt_s[1]) atomicAdd(&counters[1], cnt_s[1]);
  }
  if (i >= N) return;
  unsigned m = rng_m(i, lab, kf0, kf1, kb0, kb1, N);
  marr[i] = m;
  meta[i] = (mt & 0xFFF) | ((lab + 1) << 12);
  if (lab >= 0) {
    int s = lab ? 0 : 1;
    unsigned long long key = ((unsigned long long)m << 19) | (unsigned)i;
    atomicAdd(&hist[s * 16384 + (int)(key >> 28)], 1);
  }
}

__global__ void __launch_bounds__(256) kcollect(const int* __restrict__ counters,
        const int* __restrict__ hist, const int* __restrict__ meta,
        const unsigned* __restrict__ marr, int* __restrict__ binsel_g,
        int* __restrict__ colcnt, unsigned long long* __restrict__ collected, int N) {
  __shared__ int part[256];
  __shared__ int sbin[2], srank[2];
  const int t = threadIdx.x;
  int fgc = counters[0], bgc = counters[1];
  int fgk = min(fgc, 128);
  int Ks[2] = { fgk, min(256 - fgk, bgc) };
  for (int s = 0; s < 2; ++s) {
    int K = Ks[s];
    if (K <= 0) {
      if (t == 0) { sbin[s] = -1; srank[s] = 0; }
      __syncthreads();
      continue;
    }
    const int* h = hist + s * 16384;
    int sum = 0;
    #pragma unroll
    for (int b = 0; b < 64; ++b) sum += h[t * 64 + b];
    part[t] = sum;
    __syncthreads();
    if (t == 0) {
      int cum = 0, rch = K, chunk = 255;
      for (int q = 0; q < 256; ++q) {
        if (cum + part[q] >= K) { chunk = q; rch = K - cum; break; }
        cum += part[q];
      }
      int cum2 = 0;
      for (int b = 0; b < 64; ++b) {
        int hv = h[chunk * 64 + b];
        if (cum2 + hv >= rch) { sbin[s] = chunk * 64 + b; srank[s] = rch - cum2; break; }
        cum2 += hv;
      }
    }
    __syncthreads();
  }
  if (blockIdx.x == 0 && t < 2) { binsel_g[t] = sbin[t]; binsel_g[2 + t] = srank[t]; }
  const int b0 = sbin[0], b1 = sbin[1];
  int stride = gridDim.x * blockDim.x;
  for (int i = blockIdx.x * blockDim.x + t; i < N; i += stride) {
    int lab = ((meta[i] >> 12) & 3) - 1;
    if (lab < 0) continue;
    int s = lab ? 0 : 1;
    unsigned long long key = ((unsigned long long)marr[i] << 19) | (unsigned)i;
    if ((int)(key >> 28) != (s ? b1 : b0)) continue;
    int slot = atomicAdd(&colcnt[s], 1);
    if (slot < 1024) collected[s * 1024 + slot] = key;
  }
}

__global__ void __launch_bounds__(256) k3_out(const float4* __restrict__ anch,
        const float* __restrict__ gt, const int* __restrict__ meta,
        const unsigned* __restrict__ marr, const int* __restrict__ counters,
        const int* __restrict__ binsel_g, const int* __restrict__ colcnt,
        const unsigned long long* __restrict__ collected,
        float* __restrict__ out, int N) {
  __shared__ unsigned long long skeys[1024];
  __shared__ unsigned long long sthr[2];
  const int t = threadIdx.x;
  int fgc = counters[0], bgc = counters[1];
  int fgk = min(fgc, 128);
  int Ks[2] = { fgk, min(256 - fgk, bgc) };
  for (int s = 0; s < 2; ++s) {
    if (Ks[s] <= 0) {
      if (t == 0) sthr[s] = 0ull;
      __syncthreads(); __syncthreads();
      continue;
    }
    int n = min(colcnt[s], 1024);
    int r = binsel_g[2 + s];
    for (int kk = t; kk < n; kk += 256) skeys[kk] = collected[s * 1024 + kk];
    __syncthreads();
    for (int kk = t; kk < n; kk += 256) {
      unsigned long long k = skeys[kk];
      int rank = 0;
      for (int u = 0; u < n; ++u) rank += (skeys[u] < k);
      if (rank == r - 1) sthr[s] = k + 1ull;
    }
    __syncthreads();
  }
  const int ne = fgk + min(256 - fgk, bgc);
  int i = blockIdx.x * blockDim.x + t;
  if (i >= N) return;
  int mt = meta[i];
  int lab = ((mt >> 12) & 3) - 1;
  bool inside = (mt >> 9) & 1;
  int am = mt & 0x1FF;
  float4 a = make_float4(0.f, 0.f, 0.f, 0.f);
  if (inside) a = anch[i];
  // reuse write_out_one's logic inline (am indexes gt, not sg)
  int labf = lab;
  if (labf >= 0) {
    int s = labf ? 0 : 1;
    unsigned long long key = ((unsigned long long)marr[i] << 19) | (unsigned)i;
    if (key >= sthr[s]) labf = -1;
  }
  out[i] = (float)labf;
  float4 tg = make_float4(0.0f, 0.0f, 0.0f, 0.0f);
  if (inside) {
    float g0 = gt[5*am], g1 = gt[5*am+1], g2 = gt[5*am+2], g3 = gt[5*am+3];
    float ew = __fadd_rn(__fsub_rn(a.z, a.x), 1.0f);
    float eh = __fadd_rn(__fsub_rn(a.w, a.y), 1.0f);
    float ecx = __fadd_rn(a.x, __fmul_rn(0.5f, ew));
    float ecy = __fadd_rn(a.y, __fmul_rn(0.5f, eh));
    float gw = __fadd_rn(__fsub_rn(g2, g0), 1.0f);
    float gh = __fadd_rn(__fsub_rn(g3, g1), 1.0f);
    float gcx = __fadd_rn(g0, __fmul_rn(0.5f, gw));
    float gcy = __fadd_rn(g1, __fmul_rn(0.5f, gh));
    tg = make_float4(__fdiv_rn(__fsub_rn(gcx, ecx), ew),
                     __fdiv_rn(__fsub_rn(gcy, ecy), eh),
                     logf(__fdiv_rn(gw, ew)),
                     logf(__fdiv_rn(gh, eh)));
  }
  reinterpret_cast<float4*>(out + (size_t)N)[i] = tg;
  float bw = (labf == 1) ? 1.0f : 0.0f;
  reinterpret_cast<float4*>(out + 5 * (size_t)N)[i] = make_float4(bw, bw, bw, bw);
  float ov = (labf >= 0) ? __fdiv_rn(1.0f, (float)ne) : 0.0f;
  reinterpret_cast<float4*>(out + 9 * (size_t)N)[i] = make_float4(ov, ov, ov, ov);
}

// ---------------- launch ----------------
extern "C" void kernel_launch(void* const* d_in, const int* in_sizes, int n_in,
                              void* d_out, int out_size, void* d_ws, size_t ws_size,
                              hipStream_t stream) {
  const float4* anch = (const float4*)d_in[3];
  const float* gt    = (const float*)d_in[1];
  const float* info  = (const float*)d_in[2];
  float* out = (float*)d_out;
  int N = in_sizes[3] / 4;                 // 331776 (< 2^19 for key packing)
  int G = in_sizes[1] / 5;                 // 128 (must be <= 128)
  const int NCH = (N + 255) / 256;         // 1296

  // workspace layout (r11-compatible)
  char* ws = (char*)d_ws;
  int* counters = (int*)(ws + 0);                 // 2 ints
  int* colcnt   = (int*)(ws + 8);                 // 2 ints
  int* binsel   = (int*)(ws + 16);                // bin[2], rank[2]
  int* gmax     = (int*)(ws + 64);                // 128 ints
  int* hist     = (int*)(ws + 1024);              // 2*16384 ints -> 132096
  unsigned long long* collected = (unsigned long long*)(ws + 132096); // 2*1024 u64
  float* slab    = (float*)(ws + 148480);         // NCH*128 floats (fallback only)
  size_t slab_end = 148480 + (size_t)NCH * 128 * 4;
  unsigned* marr = (unsigned*)(ws + slab_end);
  int* meta      = (int*)(ws + slab_end + 4ull * (size_t)N);

  // host-side key derivation: kf, kb = split(key(42))
  uint32_t kf0, kf1, kb0, kb1;
#if RNG_PARTITIONABLE
  tf2x32(0u, 42u, 0u, 0u, kf0, kf1);
  tf2x32(0u, 42u, 0u, 1u, kb0, kb1);
#else
  {
    uint32_t a0, a1, b0, b1;
    tf2x32(0u, 42u, 0u, 2u, a0, a1);
    tf2x32(0u, 42u, 1u, 3u, b0, b1);
    kf0 = a0; kf1 = b0; kb0 = a1; kb1 = b1;
  }
#endif

  // mega grid: 2 anchors/thread
  int halfN = (N + 1) >> 1;
  int NB = (halfN + 255) / 256;            // 648
  int hs = NB * 256;                       // 165888

  // host-side gates (graph-capture safe: no stream ops)
  int dev = 0; (void)hipGetDevice(&dev);
  int coop = 0; (void)hipDeviceGetAttribute(&coop, hipDeviceAttributeCooperativeLaunch, dev);
  int cus = 0;  (void)hipDeviceGetAttribute(&cus, hipDeviceAttributeMultiprocessorCount, dev);
  int occ = 0;  (void)hipOccupancyMaxActiveBlocksPerMultiprocessor(&occ, mega, 256, 0);
  bool use_coop = (coop != 0) && (occ > 0) && ((long long)occ * (long long)cus >= (long long)NB);

  hipError_t err = hipErrorUnknown;
  if (use_coop) {
    void* args[] = { (void*)&anch, (void*)&gt, (void*)&info, (void*)&out,
                     (void*)&gmax, (void*)&hist, (void*)&counters, (void*)&colcnt,
                     (void*)&collected, (void*)&kf0, (void*)&kf1, (void*)&kb0,
                     (void*)&kb1, (void*)&N, (void*)&G, (void*)&hs };
    err = hipLaunchCooperativeKernel((void*)mega, dim3(NB), dim3(256), args, 0, stream);
  }
  if (!use_coop || err != hipSuccess) {
    (void)hipGetLastError();               // clear any sticky error
    K1a<<<NCH, 256, 0, stream>>>(anch, gt, info, meta, slab, hist, (int*)ws, N, G);
    kgtB<<<G, 256, 0, stream>>>(slab, gmax, NCH);
    K1c<<<NCH, 256, 0, stream>>>(anch, gt, gmax, meta, marr, counters, hist,
                                 kf0, kf1, kb0, kb1, N, G);
    kcollect<<<128, 256, 0, stream>>>(counters, hist, meta, marr, binsel,
                                      colcnt, collected, N);
    k3_out<<<NCH, 256, 0, stream>>>(anch, gt, meta, marr, counters, binsel,
                                    colcnt, collected, out, N);
  }
}

// Round 14
// 68.603 us; speedup vs baseline: 4.5716x; 4.5716x over previous
//
#include <hip/hip_runtime.h>
#include <cstdint>

#define RNG_PARTITIONABLE 1

// ---------------- Threefry-2x32 (exact JAX schedule) ----------------
__host__ __device__ inline void tf2x32(uint32_t k0, uint32_t k1,
                                       uint32_t x0, uint32_t x1,
                                       uint32_t& o0, uint32_t& o1) {
  const uint32_t k2 = k0 ^ k1 ^ 0x1BD11BDAu;
#define ROT(v, r) (((v) << (r)) | ((v) >> (32 - (r))))
#define R4(a,b,c,d) \
  x0 += x1; x1 = ROT(x1, a); x1 ^= x0; \
  x0 += x1; x1 = ROT(x1, b); x1 ^= x0; \
  x0 += x1; x1 = ROT(x1, c); x1 ^= x0; \
  x0 += x1; x1 = ROT(x1, d); x1 ^= x0;
  x0 += k0; x1 += k1;
  R4(13,15,26,6)   x0 += k1; x1 += k2 + 1u;
  R4(17,29,16,24)  x0 += k2; x1 += k0 + 2u;
  R4(13,15,26,6)   x0 += k0; x1 += k1 + 3u;
  R4(17,29,16,24)  x0 += k1; x1 += k2 + 4u;
  R4(13,15,26,6)   x0 += k2; x1 += k0 + 5u;
  o0 = x0; o1 = x1;
#undef R4
#undef ROT
}

// ---------------- exact (contraction-free, IEEE) IoU ----------------
__device__ __forceinline__ float iou_fn(float ax0, float ay0, float ax1, float ay1,
                                        float g0, float g1, float g2, float g3,
                                        float area_a, float area_g) {
  float ix0 = fmaxf(ax0, g0);
  float iy0 = fmaxf(ay0, g1);
  float ix1 = fminf(ax1, g2);
  float iy1 = fminf(ay1, g3);
  float iw = fmaxf(__fsub_rn(ix1, ix0), 0.0f);
  float ih = fmaxf(__fsub_rn(iy1, iy0), 0.0f);
  float inter = __fmul_rn(iw, ih);
  float denom = __fadd_rn(__fsub_rn(__fadd_rn(area_a, area_g), inter), 1e-5f);
  return __fdiv_rn(inter, denom);
}

__device__ __forceinline__ float area_fn(float x0, float y0, float x1, float y1) {
  return __fmul_rn(fmaxf(__fsub_rn(x1, x0), 0.0f), fmaxf(__fsub_rn(y1, y0), 0.0f));
}

// ---------------- K1a: anchor-major; wave pass-mask; fused per-gt slab -------
// Also zeroes hist (32768 ints) + counters/colcnt (4 ints) for the LATER
// kernels (K1c/kcollect) -- kernel-boundary ordering guarantees visibility.
__global__ void __launch_bounds__(256) K1a(const float4* __restrict__ anch,
        const float* __restrict__ gt, const float* __restrict__ info,
        int* __restrict__ meta, float* __restrict__ slab,
        int* __restrict__ hist, int* __restrict__ zbase, int N, int G) {
  __shared__ float4 sg[128];
  __shared__ int smax[128];
  const int t = threadIdx.x;
  const int gtid = blockIdx.x * 256 + t;
  if (gtid < 2 * 16384) hist[gtid] = 0;     // consumed by K1c (later kernel)
  if (gtid < 4) zbase[gtid] = 0;            // counters[0..1], colcnt[0..1]
  for (int q = t; q < G; q += 256) {
    float g0 = gt[5*q], g1 = gt[5*q+1], g2 = gt[5*q+2], g3 = gt[5*q+3];
    sg[q] = make_float4(g0, g1, g2, g3);
    smax[q] = 0;                       // 0.0f bits (valid: true gt-max >= 0)
  }
  __syncthreads();
  const float Himg = info[0], Wimg = info[1];
  const int i = gtid;
  float4 a = make_float4(0.f, 0.f, 0.f, 0.f);
  bool inside = false;
  float area_a = 0.f;
  float ex0 = INFINITY, ey0 = INFINITY, ex1 = -INFINITY, ey1 = -INFINITY;
  if (i < N) {
    a = anch[i];
    inside = (a.x >= 0.f) && (a.y >= 0.f) && (a.z < Wimg) && (a.w < Himg);
    if (inside) { ex0 = a.x; ey0 = a.y; ex1 = a.z; ey1 = a.w; }
    area_a = area_fn(a.x, a.y, a.z, a.w);
  }
  // wave bbox over inside lanes (conservative superset test)
  float wx0 = ex0, wy0 = ey0, wx1 = ex1, wy1 = ey1;
  #pragma unroll
  for (int d = 32; d; d >>= 1) {
    wx0 = fminf(wx0, __shfl_xor(wx0, d));
    wy0 = fminf(wy0, __shfl_xor(wy0, d));
    wx1 = fmaxf(wx1, __shfl_xor(wx1, d));
    wy1 = fmaxf(wy1, __shfl_xor(wy1, d));
  }
  // wave-uniform pass masks: lane l tests gt l and gt l+64
  const int l = t & 63;
  bool p0 = false, p1 = false;
  if (l < G) {
    float4 p = sg[l];
    p0 = (wx0 < p.z) && (p.x < wx1) && (wy0 < p.w) && (p.y < wy1);
  }
  if (l + 64 < G) {
    float4 p = sg[l + 64];
    p1 = (wx0 < p.z) && (p.x < wx1) && (wy0 < p.w) && (p.y < wy1);
  }
  unsigned long long m0 = __ballot(p0);
  unsigned long long m1 = __ballot(p1);
  float best = inside ? 0.0f : -1.0f;  // all-skip rows: argmax = 0 (matches ref)
  int bj = 0;
  const int lane0 = (l == 0);
  while (m0) {                                          // j ascending in [0,64)
    int j = __ffsll(m0) - 1; m0 &= m0 - 1;
    float4 p = sg[j];
    float ag = area_fn(p.x, p.y, p.z, p.w);
    float iou = iou_fn(a.x, a.y, a.z, a.w, p.x, p.y, p.z, p.w, area_a, ag);
    float mval = inside ? iou : -1.0f;
    if (mval > best) { best = mval; bj = j; }           // strict >: FIRST argmax
    float w = mval;                                     // exact fmax reduce
    #pragma unroll
    for (int d = 32; d; d >>= 1) w = fmaxf(w, __shfl_xor(w, d));
    if (lane0) atomicMax(&smax[j], __float_as_int(w));
  }
  while (m1) {                                          // then [64,128) ascending
    int j = __ffsll(m1) - 1 + 64; m1 &= m1 - 1;
    float4 p = sg[j];
    float ag = area_fn(p.x, p.y, p.z, p.w);
    float iou = iou_fn(a.x, a.y, a.z, a.w, p.x, p.y, p.z, p.w, area_a, ag);
    float mval = inside ? iou : -1.0f;
    if (mval > best) { best = mval; bj = j; }
    float w = mval;
    #pragma unroll
    for (int d = 32; d; d >>= 1) w = fmaxf(w, __shfl_xor(w, d));
    if (lane0) atomicMax(&smax[j], __float_as_int(w));
  }
  if (i < N) {
    int cls = (best < 0.3f) ? 0 : ((best >= 0.7f) ? 2 : 1);
    meta[i] = bj | (inside ? 512 : 0) | (cls << 10);
  }
  __syncthreads();
  for (int q = t; q < G; q += 256)
    slab[(size_t)blockIdx.x * 128 + q] = __int_as_float(smax[q]);
}

// ---------------- kgtB: reduce slab column -> gmax ---------------------------
__global__ void __launch_bounds__(256) kgtB(const float* __restrict__ slab,
                                            int* __restrict__ gmax, int nchunks) {
  __shared__ float red[256];
  const int t = threadIdx.x;
  const int j = blockIdx.x;
  float best = 0.0f;
  for (int c = t; c < nchunks; c += 256)
    best = fmaxf(best, slab[(size_t)c * 128 + j]);
  red[t] = best;
  __syncthreads();
  #pragma unroll
  for (int s = 128; s > 0; s >>= 1) {
    if (t < s) red[t] = fmaxf(red[t], red[t + s]);
    __syncthreads();
  }
  if (t == 0) gmax[j] = __float_as_int(red[0]);
}

// ---------------- K1c: labels (is_gt_best only for mid class) + rng + hist ---
__global__ void __launch_bounds__(256) K1c(const float4* __restrict__ anch,
        const float* __restrict__ gt, const int* __restrict__ gmax,
        int* __restrict__ meta, unsigned* __restrict__ marr,
        int* __restrict__ counters, int* __restrict__ hist,
        uint32_t kf0, uint32_t kf1, uint32_t kb0, uint32_t kb1,
        int N, int G) {
  __shared__ float4 sg[128];
  __shared__ float sgm[128];
  __shared__ int cnt_s[2];
  __shared__ int zlist[16];
  __shared__ int zn;
  const int t = threadIdx.x;
  if (t == 0) zn = 0;
  if (t < 2) cnt_s[t] = 0;
  for (int q = t; q < G; q += 256) {
    float g0 = gt[5*q], g1 = gt[5*q+1], g2 = gt[5*q+2], g3 = gt[5*q+3];
    sg[q] = make_float4(g0, g1, g2, g3);
    float gm = __int_as_float(gmax[q]);
    sgm[q] = gm;
    if (gm == 0.0f) { int p = atomicAdd(&zn, 1); if (p < 16) zlist[p] = q; }
  }
  __syncthreads();
  const int i = blockIdx.x * 256 + t;
  int mt = 0; bool inside = false; int cls = 0;
  float4 a = make_float4(0.f, 0.f, 0.f, 0.f);
  if (i < N) {
    mt = meta[i];
    inside = (mt >> 9) & 1;
    cls = (mt >> 10) & 3;
  }
  const bool need = (i < N) && inside && (cls == 1);
  bool gbest = false;
  if (__any(need)) {
    float area_a = 0.f;
    if (i < N) { a = anch[i]; area_a = area_fn(a.x, a.y, a.z, a.w); }
    float ex0 = need ? a.x : INFINITY,  ey0 = need ? a.y : INFINITY;
    float ex1 = need ? a.z : -INFINITY, ey1 = need ? a.w : -INFINITY;
    float wx0 = ex0, wy0 = ey0, wx1 = ex1, wy1 = ey1;
    #pragma unroll
    for (int d = 32; d; d >>= 1) {
      wx0 = fminf(wx0, __shfl_xor(wx0, d));
      wy0 = fminf(wy0, __shfl_xor(wy0, d));
      wx1 = fmaxf(wx1, __shfl_xor(wx1, d));
      wy1 = fmaxf(wy1, __shfl_xor(wy1, d));
    }
    const int l = t & 63;
    bool p0 = false, p1 = false;
    if (l < G) {
      float4 p = sg[l];
      p0 = (wx0 < p.z) && (p.x < wx1) && (wy0 < p.w) && (p.y < wy1);
    }
    if (l + 64 < G) {
      float4 p = sg[l + 64];
      p1 = (wx0 < p.z) && (p.x < wx1) && (wy0 < p.w) && (p.y < wy1);
    }
    unsigned long long m0 = __ballot(p0);
    unsigned long long m1 = __ballot(p1);
    while (m0) {
      int j = __ffsll(m0) - 1; m0 &= m0 - 1;
      float4 p = sg[j];
      float ag = area_fn(p.x, p.y, p.z, p.w);
      float iou = iou_fn(a.x, a.y, a.z, a.w, p.x, p.y, p.z, p.w, area_a, ag);
      gbest = gbest | (need && (iou == sgm[j]));
    }
    while (m1) {
      int j = __ffsll(m1) - 1 + 64; m1 &= m1 - 1;
      float4 p = sg[j];
      float ag = area_fn(p.x, p.y, p.z, p.w);
      float iou = iou_fn(a.x, a.y, a.z, a.w, p.x, p.y, p.z, p.w, area_a, ag);
      gbest = gbest | (need && (iou == sgm[j]));
    }
    // exact handling of degenerate gmax==0 gts: iou==0==gmax  <=>  no overlap
    for (int z = 0; z < 16; ++z) {
      if (z >= zn) break;
      float4 p = sg[zlist[z]];
      bool ov = (a.x < p.z) && (p.x < a.z) && (a.y < p.w) && (p.y < a.w);
      gbest = gbest | (need && !ov);
    }
  }
  int lab = -1;
  if (i < N && inside)
    lab = (cls == 0) ? 0 : ((cls == 2) ? 1 : (gbest ? 1 : -1));
  unsigned long long bf = __ballot(lab == 1), bb = __ballot(lab == 0);
  if ((t & 63) == 0) {
    if (bf) atomicAdd(&cnt_s[0], __popcll(bf));
    if (bb) atomicAdd(&cnt_s[1], __popcll(bb));
  }
  __syncthreads();
  if (t == 0) {
    if (cnt_s[0]) atomicAdd(&counters[0], cnt_s[0]);
    if (cnt_s[1]) atomicAdd(&counters[1], cnt_s[1]);
  }
  if (i >= N) return;
  // rng needed only where some lane in the wave is labeled (marr of unlabeled
  // anchors is never read by kcollect/k3)
  unsigned m = 0;
  if (__any(lab >= 0)) {
    uint32_t Kk0 = (lab == 1) ? kf0 : kb0;
    uint32_t Kk1 = (lab == 1) ? kf1 : kb1;
    uint32_t o0, o1;
#if RNG_PARTITIONABLE
    tf2x32(Kk0, Kk1, 0u, (uint32_t)i, o0, o1);
    m = (o0 ^ o1) >> 9;
#else
    int NH = N >> 1;
    if (i < NH) { tf2x32(Kk0, Kk1, (uint32_t)i, (uint32_t)(i + NH), o0, o1); m = o0 >> 9; }
    else        { tf2x32(Kk0, Kk1, (uint32_t)(i - NH), (uint32_t)i, o0, o1); m = o1 >> 9; }
#endif
  }
  marr[i] = m;
  meta[i] = (mt & 0xFFF) | ((lab + 1) << 12);
  if (lab >= 0) {
    int s = lab ? 0 : 1;
    unsigned long long key = ((unsigned long long)m << 19) | (unsigned)i;
    atomicAdd(&hist[s * 16384 + (int)(key >> 28)], 1);
  }
}

// ---------------- kcollect (+resolveA prologue per block) --------------------
__global__ void __launch_bounds__(256) kcollect(const int* __restrict__ counters,
        const int* __restrict__ hist, const int* __restrict__ meta,
        const unsigned* __restrict__ marr, int* __restrict__ binsel_g,
        int* __restrict__ colcnt, unsigned long long* __restrict__ collected, int N) {
  __shared__ int part[256];
  __shared__ int sbin[2], srank[2];
  __shared__ int schunk;
  const int t = threadIdx.x;
  int fgc = counters[0], bgc = counters[1];
  int fgk = min(fgc, 128);
  int Ks[2] = { fgk, min(256 - fgk, bgc) };
  for (int s = 0; s < 2; ++s) {
    int K = Ks[s];
    if (K <= 0) {                        // uniform branch
      if (t == 0) { sbin[s] = -1; srank[s] = 0; }
      __syncthreads();
      continue;
    }
    const int* h = hist + s * 16384;
    int sum = 0;
    #pragma unroll
    for (int b = 0; b < 64; ++b) sum += h[t * 64 + b];
    part[t] = sum;
    __syncthreads();
    if (t == 0) {
      int cum = 0, rch = K; schunk = 255;
      for (int q = 0; q < 256; ++q) {
        if (cum + part[q] >= K) { schunk = q; rch = K - cum; break; }
        cum += part[q];
      }
      int cum2 = 0;
      for (int b = 0; b < 64; ++b) {
        int hv = h[schunk * 64 + b];
        if (cum2 + hv >= rch) { sbin[s] = schunk * 64 + b; srank[s] = rch - cum2; break; }
        cum2 += hv;
      }
    }
    __syncthreads();
  }
  if (blockIdx.x == 0 && t < 2) { binsel_g[t] = sbin[t]; binsel_g[2 + t] = srank[t]; }
  const int b0 = sbin[0], b1 = sbin[1];
  int stride = gridDim.x * blockDim.x;
  for (int i = blockIdx.x * blockDim.x + t; i < N; i += stride) {
    int lab = ((meta[i] >> 12) & 3) - 1;
    if (lab < 0) continue;
    int s = lab ? 0 : 1;
    unsigned long long key = ((unsigned long long)marr[i] << 19) | (unsigned)i;
    if ((int)(key >> 28) != (s ? b1 : b0)) continue;
    int slot = atomicAdd(&colcnt[s], 1);
    if (slot < 1024) collected[s * 1024 + slot] = key;
  }
}

// ---------------- k3 (+resolveB prologue): final outputs ---------------------
__global__ void __launch_bounds__(256) k3_out(const float4* __restrict__ anch,
        const float* __restrict__ gt, const int* __restrict__ meta,
        const unsigned* __restrict__ marr, const int* __restrict__ counters,
        const int* __restrict__ binsel_g, const int* __restrict__ colcnt,
        const unsigned long long* __restrict__ collected,
        float* __restrict__ out, int N) {
  __shared__ unsigned long long skeys[1024];
  __shared__ unsigned long long sthr[2];
  const int t = threadIdx.x;
  int fgc = counters[0], bgc = counters[1];
  int fgk = min(fgc, 128);
  int Ks[2] = { fgk, min(256 - fgk, bgc) };
  for (int s = 0; s < 2; ++s) {
    if (Ks[s] <= 0) {                    // uniform
      if (t == 0) sthr[s] = 0ull;
      __syncthreads(); __syncthreads();
      continue;
    }
    int n = min(colcnt[s], 1024);
    int r = binsel_g[2 + s];
    for (int kk = t; kk < n; kk += 256) skeys[kk] = collected[s * 1024 + kk];
    __syncthreads();
    for (int kk = t; kk < n; kk += 256) {
      unsigned long long k = skeys[kk];
      int rank = 0;
      for (int u = 0; u < n; ++u) rank += (skeys[u] < k);
      if (rank == r - 1) sthr[s] = k + 1ull;  // keep iff key < thr
    }
    __syncthreads();
  }
  const int ne = fgk + min(256 - fgk, bgc);
  int i = blockIdx.x * blockDim.x + t;
  if (i >= N) return;
  int mt = meta[i];
  int lab = ((mt >> 12) & 3) - 1;
  bool inside = (mt >> 9) & 1;
  int am = mt & 0x1FF;
  if (lab >= 0) {
    int s = lab ? 0 : 1;
    unsigned long long key = ((unsigned long long)marr[i] << 19) | (unsigned)i;
    if (key >= sthr[s]) lab = -1;
  }
  out[i] = (float)lab;
  float4 tg = make_float4(0.0f, 0.0f, 0.0f, 0.0f);
  if (inside) {
    float4 a = anch[i];
    float g0 = gt[5*am], g1 = gt[5*am+1], g2 = gt[5*am+2], g3 = gt[5*am+3];
    float ew = __fadd_rn(__fsub_rn(a.z, a.x), 1.0f);
    float eh = __fadd_rn(__fsub_rn(a.w, a.y), 1.0f);
    float ecx = __fadd_rn(a.x, __fmul_rn(0.5f, ew));
    float ecy = __fadd_rn(a.y, __fmul_rn(0.5f, eh));
    float gw = __fadd_rn(__fsub_rn(g2, g0), 1.0f);
    float gh = __fadd_rn(__fsub_rn(g3, g1), 1.0f);
    float gcx = __fadd_rn(g0, __fmul_rn(0.5f, gw));
    float gcy = __fadd_rn(g1, __fmul_rn(0.5f, gh));
    tg = make_float4(__fdiv_rn(__fsub_rn(gcx, ecx), ew),
                     __fdiv_rn(__fsub_rn(gcy, ecy), eh),
                     logf(__fdiv_rn(gw, ew)),
                     logf(__fdiv_rn(gh, eh)));
  }
  reinterpret_cast<float4*>(out + (size_t)N)[i] = tg;
  float bw = (lab == 1) ? 1.0f : 0.0f;
  reinterpret_cast<float4*>(out + 5 * (size_t)N)[i] = make_float4(bw, bw, bw, bw);
  float ov = (lab >= 0) ? __fdiv_rn(1.0f, (float)ne) : 0.0f;
  reinterpret_cast<float4*>(out + 9 * (size_t)N)[i] = make_float4(ov, ov, ov, ov);
}

// ---------------- launch ----------------
extern "C" void kernel_launch(void* const* d_in, const int* in_sizes, int n_in,
                              void* d_out, int out_size, void* d_ws, size_t ws_size,
                              hipStream_t stream) {
  const float4* anch = (const float4*)d_in[3];
  const float* gt    = (const float*)d_in[1];
  const float* info  = (const float*)d_in[2];
  float* out = (float*)d_out;
  const int N = in_sizes[3] / 4;                 // 331776 (< 2^19 for key packing)
  const int G = in_sizes[1] / 5;                 // 128 (must be <= 128)
  const int NCH = (N + 255) / 256;               // 1296 chunks

  // workspace layout (~3.31 MB)
  char* ws = (char*)d_ws;
  int* counters = (int*)(ws + 0);                // 2 ints
  int* colcnt   = (int*)(ws + 8);                // 2 ints
  int* binsel   = (int*)(ws + 16);               // bin[2], rank[2]
  int* gmax     = (int*)(ws + 64);               // 128 ints (float bits)
  int* hist     = (int*)(ws + 1024);             // 2*16384 ints -> end 132096
  unsigned long long* collected = (unsigned long long*)(ws + 132096); // 2*1024 u64 -> 148480
  float* slab    = (float*)(ws + 148480);        // NCH*128 floats
  size_t slab_end = 148480 + (size_t)NCH * 128 * 4;
  unsigned* marr = (unsigned*)(ws + slab_end);
  int* meta      = (int*)(ws + slab_end + 4ull * (size_t)N);

  // host-side key derivation: kf, kb = split(key(42))
  uint32_t kf0, kf1, kb0, kb1;
#if RNG_PARTITIONABLE
  tf2x32(0u, 42u, 0u, 0u, kf0, kf1);
  tf2x32(0u, 42u, 0u, 1u, kb0, kb1);
#else
  {
    uint32_t a0, a1, b0, b1;
    tf2x32(0u, 42u, 0u, 2u, a0, a1);
    tf2x32(0u, 42u, 1u, 3u, b0, b1);
    kf0 = a0; kf1 = b0; kb0 = a1; kb1 = b1;
  }
#endif

  K1a<<<NCH, 256, 0, stream>>>(anch, gt, info, meta, slab, hist, (int*)ws, N, G);
  kgtB<<<G, 256, 0, stream>>>(slab, gmax, NCH);
  K1c<<<NCH, 256, 0, stream>>>(anch, gt, gmax, meta, marr, counters, hist,
                               kf0, kf1, kb0, kb1, N, G);
  kcollect<<<128, 256, 0, stream>>>(counters, hist, meta, marr, binsel,
                                    colcnt, collected, N);
  k3_out<<<NCH, 256, 0, stream>>>(anch, gt, meta, marr, counters, binsel,
                                  colcnt, collected, out, N);
}